// Round 5
// baseline (462.813 us; speedup 1.0000x reference)
//
#include <hip/hip_runtime.h>
#include <math.h>

#define NB 512
#define LL 33
#define DD 4096
#define PP 64
#define KK 512
#define HH 128
#define LN_EPS 1e-5f
#define NT 512          // 8 waves/block, 2 blocks/CU -> 16 waves/CU
#define NW (NT / 64)

// monotone float->uint key: larger float => larger key
__device__ __forceinline__ unsigned fkey(float s) {
    unsigned u = __float_as_uint(s);
    return (u & 0x80000000u) ? ~u : (u | 0x80000000u);
}

__device__ __forceinline__ float waveMax(float v) {
    #pragma unroll
    for (int o = 32; o > 0; o >>= 1) v = fmaxf(v, __shfl_xor(v, o));
    return v;
}
__device__ __forceinline__ float waveSum(float v) {
    #pragma unroll
    for (int o = 32; o > 0; o >>= 1) v += __shfl_xor(v, o);
    return v;
}

__global__ __launch_bounds__(NT) void sda_kernel(
    const float* __restrict__ x,
    const float* __restrict__ Wp, const float* __restrict__ bp,
    const float* __restrict__ ws, const float* __restrict__ bsp,
    const float* __restrict__ gamma, const float* __restrict__ beta,
    const float* __restrict__ W1, const float* __restrict__ b1,
    const float* __restrict__ W2, const float* __restrict__ b2,
    float* __restrict__ out)
{
    __shared__ __align__(16) float s_w[DD];        // scores -> unnormalized weights
    __shared__ __align__(16) float s_xc[LL * 256]; // column-cache: x[b, l, 0:256]
    __shared__ float s_v[LL];
    __shared__ unsigned s_hist[NW][256];
    __shared__ unsigned s_scanA[256];
    __shared__ unsigned s_scanB[256];
    __shared__ float s_red[NW];
    __shared__ float s_y[LL];
    __shared__ float s_o[PP];
    __shared__ float s_g[HH];
    __shared__ float s_c, s_m, s_S;
    __shared__ unsigned s_prefix, s_kk, s_ceq;

    const int t = threadIdx.x;
    const int lane = t & 63;
    const int wv = t >> 6;
    const int b = blockIdx.x;
    const float* __restrict__ xb = x + (size_t)b * (LL * DD);

    // fold scoring: v[l] = sum_p Wp[p,l]*ws[p];  c = sum_p ws[p]*bp[p] + bs
    if (t < LL) {
        float a = 0.f;
        for (int p = 0; p < PP; ++p) a += Wp[p * LL + t] * ws[p];
        s_v[t] = a;
    } else if (t == LL) {
        float a = bsp[0];
        for (int p = 0; p < PP; ++p) a += ws[p] * bp[p];
        s_c = a;
    }
    if (t == 0) { s_prefix = 0u; s_kk = KK; s_ceq = 0u; }
    __syncthreads();

    // ---- phase A: scores[d] = v . x[b,:,d] + c
    //      software-pipelined: load row l+1 while FMA-ing row l
    const float c0 = s_c;
    float4* s_w4 = (float4*)s_w;
    float4* s_xc4 = (float4*)s_xc;   // [l*64 + f], f float4 units, cols 0..255
    const float4* rp = (const float4*)xb;           // row 0 base (1024 float4/row)
    float4 cur0 = rp[t];
    float4 cur1 = rp[t + NT];
    float4 acc0 = make_float4(c0, c0, c0, c0);
    float4 acc1 = acc0;
    for (int l = 0; l < LL - 1; ++l) {
        const float4* np = rp + 1024;
        const float4 nxt0 = np[t];
        const float4 nxt1 = np[t + NT];
        const float vl = s_v[l];
        if (t < 64) s_xc4[l * 64 + t] = cur0;       // wave-0-only LDS cache store
        acc0.x += vl * cur0.x; acc0.y += vl * cur0.y; acc0.z += vl * cur0.z; acc0.w += vl * cur0.w;
        acc1.x += vl * cur1.x; acc1.y += vl * cur1.y; acc1.z += vl * cur1.z; acc1.w += vl * cur1.w;
        cur0 = nxt0; cur1 = nxt1; rp = np;
    }
    {
        const float vl = s_v[LL - 1];
        if (t < 64) s_xc4[(LL - 1) * 64 + t] = cur0;
        acc0.x += vl * cur0.x; acc0.y += vl * cur0.y; acc0.z += vl * cur0.z; acc0.w += vl * cur0.w;
        acc1.x += vl * cur1.x; acc1.y += vl * cur1.y; acc1.z += vl * cur1.z; acc1.w += vl * cur1.w;
    }

    // keys stay in registers for all radix rounds + the weight phase
    unsigned ukey[8];
    s_w4[t] = acc0;
    s_w4[t + NT] = acc1;
    ukey[0] = fkey(acc0.x); ukey[1] = fkey(acc0.y); ukey[2] = fkey(acc0.z); ukey[3] = fkey(acc0.w);
    ukey[4] = fkey(acc1.x); ukey[5] = fkey(acc1.y); ukey[6] = fkey(acc1.z); ukey[7] = fkey(acc1.w);
    float lmax = fmaxf(fmaxf(fmaxf(acc0.x, acc0.y), fmaxf(acc0.z, acc0.w)),
                       fmaxf(fmaxf(acc1.x, acc1.y), fmaxf(acc1.z, acc1.w)));
    lmax = waveMax(lmax);
    if (lane == 0) s_red[wv] = lmax;
    __syncthreads();
    if (t == 0) {
        float m = s_red[0];
        for (int i = 1; i < NW; ++i) m = fmaxf(m, s_red[i]);
        s_m = m;
    }
    __syncthreads();

    // ---- exact radix-select of the K-th largest key (MSB->LSB, 8 bits/round)
    for (int shift = 24; shift >= 0; shift -= 8) {
        for (int i = t; i < NW * 256; i += NT) ((unsigned*)s_hist)[i] = 0u;
        __syncthreads();
        const unsigned pfx = s_prefix;
        const unsigned hm = (shift == 24) ? 0u : (0xFFFFFFFFu << (shift + 8));
        #pragma unroll
        for (int i = 0; i < 8; ++i) {
            const unsigned u = ukey[i];
            if ((u & hm) == pfx)
                atomicAdd(&s_hist[wv][(u >> shift) & 255u], 1u);
        }
        __syncthreads();
        if (t < 256) {
            unsigned a = 0;
            for (int w = 0; w < NW; ++w) a += s_hist[w][t];
            s_scanA[t] = a;
        }
        __syncthreads();
        // suffix (descending cumulative) sum, double-buffered: 1 barrier/step
        unsigned* src = s_scanA;
        unsigned* dst = s_scanB;
        for (int off = 1; off < 256; off <<= 1) {
            if (t < 256) dst[t] = src[t] + ((t + off < 256) ? src[t + off] : 0u);
            __syncthreads();
            unsigned* tmp = src; src = dst; dst = tmp;
        }
        if (t < 256) {
            const unsigned kk = s_kk;
            const unsigned mine = src[t];
            const unsigned above = (t == 255) ? 0u : src[t + 1];
            if (mine >= kk && above < kk) {   // exactly one thread/bin crosses
                s_prefix = pfx | ((unsigned)t << shift);
                s_kk = kk - above;            // remaining rank within equal keys
                s_ceq = mine - above;         // count of keys == chosen prefix
            }
        }
        __syncthreads();
    }
    const unsigned T = s_prefix;
    const unsigned need_eq = s_kk;     // how many key==T elements belong to top-K
    const unsigned count_eq = s_ceq;   // how many key==T elements exist
    const float m = s_m;

    // ---- unnormalized softmax weights in place (dense over d)
    if (count_eq == need_eq) {         // common path: take all ties
        float4 w0, w1;
        w0.x = (ukey[0] >= T) ? expf(acc0.x - m) : 0.f;
        w0.y = (ukey[1] >= T) ? expf(acc0.y - m) : 0.f;
        w0.z = (ukey[2] >= T) ? expf(acc0.z - m) : 0.f;
        w0.w = (ukey[3] >= T) ? expf(acc0.w - m) : 0.f;
        w1.x = (ukey[4] >= T) ? expf(acc1.x - m) : 0.f;
        w1.y = (ukey[5] >= T) ? expf(acc1.y - m) : 0.f;
        w1.z = (ukey[6] >= T) ? expf(acc1.z - m) : 0.f;
        w1.w = (ukey[7] >= T) ? expf(acc1.w - m) : 0.f;
        s_w4[t] = w0;
        s_w4[t + NT] = w1;
        float lsum = w0.x + w0.y + w0.z + w0.w + w1.x + w1.y + w1.z + w1.w;
        lsum = waveSum(lsum);
        if (lane == 0) s_red[wv] = lsum;
        __syncthreads();
        if (t == 0) {
            float S = 0.f;
            for (int i = 0; i < NW; ++i) S += s_red[i];
            s_S = S;
        }
        __syncthreads();
    } else {
        // rare tie-at-threshold path: serial, exact lowest-index tie-break
        __syncthreads();
        if (t == 0) {
            unsigned taken = 0;
            float S = 0.f;
            for (int d = 0; d < DD; ++d) {
                const float s = s_w[d];
                const unsigned u = fkey(s);
                float w = 0.f;
                if (u > T) w = expf(s - m);
                else if (u == T && taken < need_eq) { w = expf(s - m); ++taken; }
                s_w[d] = w;
                S += w;
            }
            s_S = S;
        }
        __syncthreads();
    }
    const float invS = 1.0f / s_S;

    // ---- y[l] = sum_d w[d] * x[b,l,d]
    //      REVERSE streaming order (l high->low, cols high->low): the tail of
    //      the slice was streamed most recently in phase A -> L3-resident.
    for (int k = 4; k >= 0; --k) {
        const int l = wv + NW * k;
        if (l < LL) {
            const float4* row = (const float4*)(xb + l * DD);
            float a = 0.f;
            #pragma unroll
            for (int j = 15; j >= 1; --j) {
                const int f = lane + j * 64;
                const float4 xv = row[f];
                const float4 w4 = s_w4[f];
                a += w4.x * xv.x + w4.y * xv.y + w4.z * xv.z + w4.w * xv.w;
            }
            {   // cols 0..255 from the LDS cache instead of HBM
                const float4 xv = s_xc4[l * 64 + lane];
                const float4 w4 = s_w4[lane];
                a += w4.x * xv.x + w4.y * xv.y + w4.z * xv.z + w4.w * xv.w;
            }
            a = waveSum(a);
            if (lane == 0) s_y[l] = a;
        }
    }
    __syncthreads();

    // ---- head: out = Wp*y*invS + bp ; LN ; GELU(W1+b1) ; W2+b2
    if (t < PP) {
        float a = 0.f;
        for (int l = 0; l < LL; ++l) a += Wp[t * LL + l] * s_y[l];
        s_o[t] = a * invS + bp[t];
    }
    __syncthreads();
    if (wv == 0) {
        const float o = s_o[lane];
        const float mu = waveSum(o) * (1.f / PP);
        const float dv = o - mu;
        const float var = waveSum(dv * dv) * (1.f / PP);
        s_o[lane] = dv * rsqrtf(var + LN_EPS) * gamma[lane] + beta[lane];
    }
    __syncthreads();
    if (t < HH) {
        float a = b1[t];
        for (int p = 0; p < PP; ++p) a += W1[t * PP + p] * s_o[p];
        s_g[t] = 0.5f * a * (1.f + erff(a * 0.70710678118654752440f));
    }
    __syncthreads();
    if (t < 2) {
        float a = b2[t];
        for (int j = 0; j < HH; ++j) a += W2[t * HH + j] * s_g[j];
        out[b * 2 + t] = a;
    }
}

extern "C" void kernel_launch(void* const* d_in, const int* in_sizes, int n_in,
                              void* d_out, int out_size, void* d_ws, size_t ws_size,
                              hipStream_t stream) {
    const float* x     = (const float*)d_in[0];
    const float* Wp    = (const float*)d_in[1];
    const float* bp    = (const float*)d_in[2];
    const float* ws    = (const float*)d_in[3];
    const float* bs    = (const float*)d_in[4];
    const float* gamma = (const float*)d_in[5];
    const float* beta  = (const float*)d_in[6];
    const float* W1    = (const float*)d_in[7];
    const float* b1    = (const float*)d_in[8];
    const float* W2    = (const float*)d_in[9];
    const float* b2    = (const float*)d_in[10];
    float* out = (float*)d_out;
    hipLaunchKernelGGL(sda_kernel, dim3(NB), dim3(NT), 0, stream,
                       x, Wp, bp, ws, bs, gamma, beta, W1, b1, W2, b2, out);
}

// Round 6
// 414.102 us; speedup vs baseline: 1.1176x; 1.1176x over previous
//
#include <hip/hip_runtime.h>
#include <math.h>

#define NB 512
#define LL 33
#define DD 4096
#define PP 64
#define KK 512
#define HH 128
#define LN_EPS 1e-5f
#define NT 512          // 8 waves/block, 2 blocks/CU -> 16 waves/CU
#define NW (NT / 64)

// monotone float->uint key: larger float => larger key
__device__ __forceinline__ unsigned fkey(float s) {
    unsigned u = __float_as_uint(s);
    return (u & 0x80000000u) ? ~u : (u | 0x80000000u);
}

__device__ __forceinline__ float waveMax(float v) {
    #pragma unroll
    for (int o = 32; o > 0; o >>= 1) v = fmaxf(v, __shfl_xor(v, o));
    return v;
}
__device__ __forceinline__ float waveSum(float v) {
    #pragma unroll
    for (int o = 32; o > 0; o >>= 1) v += __shfl_xor(v, o);
    return v;
}

__global__ __launch_bounds__(NT, 4) void sda_kernel(
    const float* __restrict__ x,
    const float* __restrict__ Wp, const float* __restrict__ bp,
    const float* __restrict__ ws, const float* __restrict__ bsp,
    const float* __restrict__ gamma, const float* __restrict__ beta,
    const float* __restrict__ W1, const float* __restrict__ b1,
    const float* __restrict__ W2, const float* __restrict__ b2,
    float* __restrict__ out)
{
    __shared__ __align__(16) float s_w[DD];   // scores -> unnormalized weights
    __shared__ float s_v[LL];
    __shared__ unsigned s_hist[NW][256];
    __shared__ float s_red[NW];
    __shared__ float s_y[LL];
    __shared__ float s_o[PP];
    __shared__ float s_g[HH];
    __shared__ float s_c, s_m, s_S;
    __shared__ unsigned s_prefix, s_kk, s_ceq;

    const int t = threadIdx.x;
    const int lane = t & 63;
    const int wv = t >> 6;
    const int b = blockIdx.x;
    const float* __restrict__ xb = x + (size_t)b * (LL * DD);

    // fold scoring: v[l] = sum_p Wp[p,l]*ws[p];  c = sum_p ws[p]*bp[p] + bs
    if (t < LL) {
        float a = 0.f;
        for (int p = 0; p < PP; ++p) a += Wp[p * LL + t] * ws[p];
        s_v[t] = a;
    } else if (t == LL) {
        float a = bsp[0];
        for (int p = 0; p < PP; ++p) a += ws[p] * bp[p];
        s_c = a;
    }
    if (t == 0) { s_prefix = 0u; s_kk = KK; s_ceq = 0u; }
    __syncthreads();

    // ---- phase A: scores[d] = v . x[b,:,d] + c
    //      prefetch depth 4: 8 float4 loads in flight per thread (fully
    //      unrolled -> pa/pb statically indexed, stay in registers)
    const float c0 = s_c;
    float4* s_w4 = (float4*)s_w;
    const float4* base = (const float4*)xb;   // 1024 float4 per row
    float4 pa[4], pb[4];
    #pragma unroll
    for (int s = 0; s < 4; ++s) {
        pa[s] = base[s * 1024 + t];
        pb[s] = base[s * 1024 + t + NT];
    }
    float4 acc0 = make_float4(c0, c0, c0, c0);
    float4 acc1 = acc0;
    #pragma unroll
    for (int l = 0; l < LL; ++l) {
        const int s = l & 3;
        const float4 xa = pa[s];
        const float4 xc = pb[s];
        if (l + 4 < LL) {
            pa[s] = base[(l + 4) * 1024 + t];
            pb[s] = base[(l + 4) * 1024 + t + NT];
        }
        const float vl = s_v[l];
        acc0.x += vl * xa.x; acc0.y += vl * xa.y; acc0.z += vl * xa.z; acc0.w += vl * xa.w;
        acc1.x += vl * xc.x; acc1.y += vl * xc.y; acc1.z += vl * xc.z; acc1.w += vl * xc.w;
    }

    // keys stay in registers for all radix rounds + the weight phase
    unsigned ukey[8];
    s_w4[t] = acc0;
    s_w4[t + NT] = acc1;
    ukey[0] = fkey(acc0.x); ukey[1] = fkey(acc0.y); ukey[2] = fkey(acc0.z); ukey[3] = fkey(acc0.w);
    ukey[4] = fkey(acc1.x); ukey[5] = fkey(acc1.y); ukey[6] = fkey(acc1.z); ukey[7] = fkey(acc1.w);
    float lmax = fmaxf(fmaxf(fmaxf(acc0.x, acc0.y), fmaxf(acc0.z, acc0.w)),
                       fmaxf(fmaxf(acc1.x, acc1.y), fmaxf(acc1.z, acc1.w)));
    lmax = waveMax(lmax);
    if (lane == 0) s_red[wv] = lmax;
    __syncthreads();
    if (t == 0) {
        float m = s_red[0];
        for (int i = 1; i < NW; ++i) m = fmaxf(m, s_red[i]);
        s_m = m;
    }
    __syncthreads();

    // ---- exact radix-select of the K-th largest key (MSB->LSB, 8 bits/round)
    //      3 barriers/round; 256-bin suffix scan done by wave 0 via shuffles
    for (int shift = 24; shift >= 0; shift -= 8) {
        for (int i = t; i < NW * 256; i += NT) ((unsigned*)s_hist)[i] = 0u;
        __syncthreads();
        const unsigned pfx = s_prefix;
        const unsigned hm = (shift == 24) ? 0u : (0xFFFFFFFFu << (shift + 8));
        #pragma unroll
        for (int i = 0; i < 8; ++i) {
            const unsigned u = ukey[i];
            if ((u & hm) == pfx)
                atomicAdd(&s_hist[wv][(u >> shift) & 255u], 1u);
        }
        __syncthreads();
        if (t < 64) {                 // wave 0: lane owns bins 4t..4t+3
            const int b4 = t * 4;
            unsigned c0b = 0, c1b = 0, c2b = 0, c3b = 0;
            for (int w = 0; w < NW; ++w) {
                c0b += s_hist[w][b4 + 0];
                c1b += s_hist[w][b4 + 1];
                c2b += s_hist[w][b4 + 2];
                c3b += s_hist[w][b4 + 3];
            }
            // within-lane suffix sums (high bin downward)
            const unsigned s3 = c3b;
            const unsigned s2 = c2b + s3;
            const unsigned s1 = c1b + s2;
            const unsigned s0 = c0b + s1;       // total of my 4 bins
            // cross-lane inclusive suffix of totals -> exclusive
            unsigned inc = s0;
            #pragma unroll
            for (int off = 1; off < 64; off <<= 1) {
                const int src = t + off;
                const unsigned other = __shfl(inc, (src < 64) ? src : t);
                inc += (src < 64) ? other : 0u;
            }
            const unsigned excl = inc - s0;     // keys in bins of higher lanes
            const unsigned kk = s_kk;           // all lanes read before any write
            const unsigned cm0 = excl + s0, cm1 = excl + s1,
                           cm2 = excl + s2, cm3 = excl + s3;
            // cum(b) >= kk && cum(b+1) = cum(b)-count(b) < kk  (exactly one bin)
            if (cm0 >= kk && cm0 - c0b < kk) {
                s_prefix = pfx | ((unsigned)(b4 + 0) << shift);
                s_kk = kk - (cm0 - c0b); s_ceq = c0b;
            }
            if (cm1 >= kk && cm1 - c1b < kk) {
                s_prefix = pfx | ((unsigned)(b4 + 1) << shift);
                s_kk = kk - (cm1 - c1b); s_ceq = c1b;
            }
            if (cm2 >= kk && cm2 - c2b < kk) {
                s_prefix = pfx | ((unsigned)(b4 + 2) << shift);
                s_kk = kk - (cm2 - c2b); s_ceq = c2b;
            }
            if (cm3 >= kk && cm3 - c3b < kk) {
                s_prefix = pfx | ((unsigned)(b4 + 3) << shift);
                s_kk = kk - (cm3 - c3b); s_ceq = c3b;
            }
        }
        __syncthreads();
    }
    const unsigned T = s_prefix;
    const unsigned need_eq = s_kk;     // how many key==T elements belong to top-K
    const unsigned count_eq = s_ceq;   // how many key==T elements exist
    const float m = s_m;

    // ---- unnormalized softmax weights in place (dense over d)
    if (count_eq == need_eq) {         // common path: take all ties
        float4 w0, w1;
        w0.x = (ukey[0] >= T) ? expf(acc0.x - m) : 0.f;
        w0.y = (ukey[1] >= T) ? expf(acc0.y - m) : 0.f;
        w0.z = (ukey[2] >= T) ? expf(acc0.z - m) : 0.f;
        w0.w = (ukey[3] >= T) ? expf(acc0.w - m) : 0.f;
        w1.x = (ukey[4] >= T) ? expf(acc1.x - m) : 0.f;
        w1.y = (ukey[5] >= T) ? expf(acc1.y - m) : 0.f;
        w1.z = (ukey[6] >= T) ? expf(acc1.z - m) : 0.f;
        w1.w = (ukey[7] >= T) ? expf(acc1.w - m) : 0.f;
        s_w4[t] = w0;
        s_w4[t + NT] = w1;
        float lsum = w0.x + w0.y + w0.z + w0.w + w1.x + w1.y + w1.z + w1.w;
        lsum = waveSum(lsum);
        if (lane == 0) s_red[wv] = lsum;
        __syncthreads();
        if (t == 0) {
            float S = 0.f;
            for (int i = 0; i < NW; ++i) S += s_red[i];
            s_S = S;
        }
        __syncthreads();
    } else {
        // rare tie-at-threshold path: serial, exact lowest-index tie-break
        __syncthreads();
        if (t == 0) {
            unsigned taken = 0;
            float S = 0.f;
            for (int d = 0; d < DD; ++d) {
                const float s = s_w[d];
                const unsigned u = fkey(s);
                float w = 0.f;
                if (u > T) w = expf(s - m);
                else if (u == T && taken < need_eq) { w = expf(s - m); ++taken; }
                s_w[d] = w;
                S += w;
            }
            s_S = S;
        }
        __syncthreads();
    }
    const float invS = 1.0f / s_S;

    // ---- y[l] = sum_d w[d] * x[b,l,d]
    //      REVERSE streaming order (l high->low, cols high->low): the tail of
    //      the slice was streamed most recently in phase A -> L3-resident.
    for (int k = 4; k >= 0; --k) {
        const int l = wv + NW * k;
        if (l < LL) {
            const float4* row = (const float4*)(xb + l * DD);
            float a = 0.f;
            #pragma unroll
            for (int j = 15; j >= 0; --j) {
                const int f = lane + j * 64;
                const float4 xv = row[f];
                const float4 w4 = s_w4[f];
                a += w4.x * xv.x + w4.y * xv.y + w4.z * xv.z + w4.w * xv.w;
            }
            a = waveSum(a);
            if (lane == 0) s_y[l] = a;
        }
    }
    __syncthreads();

    // ---- head: out = Wp*y*invS + bp ; LN ; GELU(W1+b1) ; W2+b2
    if (t < PP) {
        float a = 0.f;
        for (int l = 0; l < LL; ++l) a += Wp[t * LL + l] * s_y[l];
        s_o[t] = a * invS + bp[t];
    }
    __syncthreads();
    if (wv == 0) {
        const float o = s_o[lane];
        const float mu = waveSum(o) * (1.f / PP);
        const float dv = o - mu;
        const float var = waveSum(dv * dv) * (1.f / PP);
        s_o[lane] = dv * rsqrtf(var + LN_EPS) * gamma[lane] + beta[lane];
    }
    __syncthreads();
    if (t < HH) {
        float a = b1[t];
        for (int p = 0; p < PP; ++p) a += W1[t * PP + p] * s_o[p];
        s_g[t] = 0.5f * a * (1.f + erff(a * 0.70710678118654752440f));
    }
    __syncthreads();
    if (t < 2) {
        float a = b2[t];
        for (int j = 0; j < HH; ++j) a += W2[t * HH + j] * s_g[j];
        out[b * 2 + t] = a;
    }
}

extern "C" void kernel_launch(void* const* d_in, const int* in_sizes, int n_in,
                              void* d_out, int out_size, void* d_ws, size_t ws_size,
                              hipStream_t stream) {
    const float* x     = (const float*)d_in[0];
    const float* Wp    = (const float*)d_in[1];
    const float* bp    = (const float*)d_in[2];
    const float* ws    = (const float*)d_in[3];
    const float* bs    = (const float*)d_in[4];
    const float* gamma = (const float*)d_in[5];
    const float* beta  = (const float*)d_in[6];
    const float* W1    = (const float*)d_in[7];
    const float* b1    = (const float*)d_in[8];
    const float* W2    = (const float*)d_in[9];
    const float* b2    = (const float*)d_in[10];
    float* out = (float*)d_out;
    hipLaunchKernelGGL(sda_kernel, dim3(NB), dim3(NT), 0, stream,
                       x, Wp, bp, ws, bs, gamma, beta, W1, b1, W2, b2, out);
}